// Round 3
// baseline (137.299 us; speedup 1.0000x reference)
//
#include <hip/hip_runtime.h>
#include <math.h>

// Geometry: feat_erb [64,1,16384,32] f32, state [1,1,32] f32.
// Outputs: feat_out [64,1,16384,32] then final_state [64,1,32], flat in d_out.
#define B   64
#define T   16384
#define F   32
#define NC  512          // chunks along t
#define L   32           // T / NC
#define FG  8            // F / 4 (float4 groups)
#define FEAT_N (B * T * F)   // 33554432

typedef float fx4 __attribute__((ext_vector_type(4)));   // native clang vector
                                                         // (works with __builtin_nontemporal_store)

static constexpr float ALPHA = 0.99f;
static constexpr float OMA   = 1.0f - 0.99f;
static constexpr float INV40 = 1.0f / 40.0f;

// Pass 1: per (b, chunk, f-group) chunk aggregate (EMA over L steps from 0).
// tid = b*4096 + chunk*8 + fg.  262144 threads, 1024 blocks.
__global__ __launch_bounds__(256)
void ema_pass1(const float* __restrict__ x, fx4* __restrict__ c) {
    int tid   = blockIdx.x * 256 + threadIdx.x;
    int fg    = tid & (FG - 1);
    int chunk = (tid >> 3) & (NC - 1);
    int b     = tid >> 12;

    const fx4* xp = reinterpret_cast<const fx4*>(x)
                  + (size_t)(b * T + chunk * L) * FG + fg;

    float sx = 0.f, sy = 0.f, sz = 0.f, sw = 0.f;
#pragma unroll 8
    for (int i = 0; i < L; ++i) {
        fx4 v = xp[(size_t)i * FG];
        sx = fmaf(ALPHA, sx, OMA * v.x);
        sy = fmaf(ALPHA, sy, OMA * v.y);
        sz = fmaf(ALPHA, sz, OMA * v.z);
        sw = fmaf(ALPHA, sw, OMA * v.w);
    }
    fx4 r; r.x = sx; r.y = sy; r.z = sz; r.w = sw;
    c[tid] = r;
}

// Pass 2: per (b, f) combine the NC chunk aggregates sequentially,
// recording each chunk's exact starting state; write final state.
__global__ __launch_bounds__(256)
void ema_pass2(const float* __restrict__ state,
               const float* __restrict__ c,
               float* __restrict__ sstart,
               float* __restrict__ fstate,
               float aL) {
    int tid = blockIdx.x * 256 + threadIdx.x;   // b*F + f
    int f   = tid & (F - 1);
    int b   = tid >> 5;

    float s = state[f];
    const float* cp = c      + (size_t)b * NC * F + f;
    float*       sp = sstart + (size_t)b * NC * F + f;
#pragma unroll 4
    for (int k = 0; k < NC; ++k) {
        sp[k * F] = s;
        s = fmaf(aL, s, cp[k * F]);
    }
    fstate[b * F + f] = s;
}

// Pass 3: rescan each chunk from its exact starting state; emit (x - s)/40.
// Non-temporal stores: keep x resident in L3 (pass1 staged it), don't let
// the output stream evict it.
__global__ __launch_bounds__(256)
void ema_pass3(const float* __restrict__ x,
               const fx4* __restrict__ sstart,
               float* __restrict__ out) {
    int tid   = blockIdx.x * 256 + threadIdx.x;
    int fg    = tid & (FG - 1);
    int chunk = (tid >> 3) & (NC - 1);
    int b     = tid >> 12;

    size_t base = (size_t)(b * T + chunk * L) * FG + fg;
    const fx4* xp = reinterpret_cast<const fx4*>(x)   + base;
    fx4*       op = reinterpret_cast<fx4*>(out)       + base;

    fx4 s0 = sstart[tid];
    float sx = s0.x, sy = s0.y, sz = s0.z, sw = s0.w;
#pragma unroll 8
    for (int i = 0; i < L; ++i) {
        fx4 v = xp[(size_t)i * FG];
        sx = fmaf(ALPHA, sx, OMA * v.x);
        sy = fmaf(ALPHA, sy, OMA * v.y);
        sz = fmaf(ALPHA, sz, OMA * v.z);
        sw = fmaf(ALPHA, sw, OMA * v.w);
        fx4 o;
        o.x = (v.x - sx) * INV40;
        o.y = (v.y - sy) * INV40;
        o.z = (v.z - sz) * INV40;
        o.w = (v.w - sw) * INV40;
        __builtin_nontemporal_store(o, op + (size_t)i * FG);
    }
}

extern "C" void kernel_launch(void* const* d_in, const int* in_sizes, int n_in,
                              void* d_out, int out_size, void* d_ws, size_t ws_size,
                              hipStream_t stream) {
    const float* x     = (const float*)d_in[0];
    const float* state = (const float*)d_in[1];
    float* out = (float*)d_out;
    float* ws  = (float*)d_ws;

    float* c      = ws;                        // B*NC*F = 1M floats (4 MB)
    float* sstart = ws + (size_t)B * NC * F;   // another 4 MB

    const float aL = (float)pow(0.99, (double)L);   // alpha^32

    ema_pass1<<<(B * NC * FG) / 256, 256, 0, stream>>>(x, (fx4*)c);
    ema_pass2<<<(B * F) / 256, 256, 0, stream>>>(state, c, sstart, out + FEAT_N, aL);
    ema_pass3<<<(B * NC * FG) / 256, 256, 0, stream>>>(x, (const fx4*)sstart, out);
}

// Round 5
// 88.305 us; speedup vs baseline: 1.5548x; 1.5548x over previous
//
#include <hip/hip_runtime.h>
#include <math.h>

// Geometry: feat_erb [64,1,16384,32] f32, state [1,1,32] f32.
// Outputs: feat_out [64,1,16384,32] then final_state [64,1,32], flat in d_out.
#define B   64
#define T   16384
#define F   32
#define NC  512          // chunks along t
#define L   32           // T / NC
#define FG  8            // F / 4 (float4 groups)
#define CPL 8            // chunks per lane in pass2 (NC / 64)
#define FEAT_N (B * T * F)   // 33554432

typedef float fx4 __attribute__((ext_vector_type(4)));

static constexpr float ALPHA = 0.99f;
static constexpr float OMA   = 1.0f - 0.99f;
static constexpr float INV40 = 1.0f / 40.0f;

// Pass 1: per (b, chunk, f-group) chunk aggregate (EMA over L steps from 0).
// tid = b*4096 + chunk*8 + fg.  262144 threads, 1024 blocks.
__global__ __launch_bounds__(256)
void ema_pass1(const float* __restrict__ x, fx4* __restrict__ c) {
    int tid   = blockIdx.x * 256 + threadIdx.x;
    int fg    = tid & (FG - 1);
    int chunk = (tid >> 3) & (NC - 1);
    int b     = tid >> 12;

    const fx4* xp = reinterpret_cast<const fx4*>(x)
                  + (size_t)(b * T + chunk * L) * FG + fg;

    float sx = 0.f, sy = 0.f, sz = 0.f, sw = 0.f;
#pragma unroll 8
    for (int i = 0; i < L; ++i) {
        fx4 v = xp[(size_t)i * FG];
        sx = fmaf(ALPHA, sx, OMA * v.x);
        sy = fmaf(ALPHA, sy, OMA * v.y);
        sz = fmaf(ALPHA, sz, OMA * v.z);
        sw = fmaf(ALPHA, sw, OMA * v.w);
    }
    fx4 r; r.x = sx; r.y = sy; r.z = sz; r.w = sw;
    c[tid] = r;
}

// Pass 2: wave-parallel affine scan.  One wave per (b,f) sequence; lane l
// owns chunks l*8 .. l*8+7.  Chunk k is the affine map s -> aL*s + c_k;
// a lane's window composes to (aL8, d).  Kogge-Stone over 64 lanes, then
// regenerate per-chunk starting states.  2048 waves -> latency fully hidden.
__global__ __launch_bounds__(256)
void ema_pass2(const float* __restrict__ state,
               const float* __restrict__ c,      // [b][chunk][f]
               float* __restrict__ sstart,       // [b][chunk][f]
               float* __restrict__ fstate,       // [b][f]
               float aL, float aL8) {
    int tid  = blockIdx.x * 256 + threadIdx.x;
    int lane = tid & 63;
    int w    = tid >> 6;          // 0..2047 = b*F + f
    int f    = w & (F - 1);
    int b    = w >> 5;

    const float* cp = c + (size_t)b * NC * F + f;

    // load this lane's 8 chunk aggregates (L2-resident, 4B stride-128B)
    float cv[CPL];
#pragma unroll
    for (int j = 0; j < CPL; ++j)
        cv[j] = cp[(size_t)(lane * CPL + j) * F];

    // intra-lane inclusive combine: window map = (aL8, d)
    float d = 0.f;
#pragma unroll
    for (int j = 0; j < CPL; ++j)
        d = fmaf(aL, d, cv[j]);

    // Kogge-Stone inclusive scan of affine maps across lanes.
    // compose (A,D) with earlier window (Aup,Dup):  D = A*Dup + D; A = A*Aup
    float A = aL8, D = d;
#pragma unroll
    for (int o = 1; o < 64; o <<= 1) {
        float Aup = __shfl_up(A, (unsigned)o, 64);
        float Dup = __shfl_up(D, (unsigned)o, 64);
        if (lane >= o) {
            D = fmaf(A, Dup, D);
            A = A * Aup;
        }
    }

    // final state (lane 63 holds inclusive map over all 512 chunks)
    float s0 = state[f];
    if (lane == 63) fstate[w] = fmaf(A, s0, D);

    // exclusive prefix for this lane = inclusive of lane-1
    float Ae = __shfl_up(A, 1u, 64);
    float De = __shfl_up(D, 1u, 64);
    if (lane == 0) { Ae = 1.f; De = 0.f; }
    float s = fmaf(Ae, s0, De);   // starting state of chunk lane*CPL

    float* sp = sstart + (size_t)b * NC * F + f;
#pragma unroll
    for (int j = 0; j < CPL; ++j) {
        sp[(size_t)(lane * CPL + j) * F] = s;
        s = fmaf(aL, s, cv[j]);
    }
}

// Pass 3: rescan each chunk from its exact starting state; emit (x - s)/40.
__global__ __launch_bounds__(256)
void ema_pass3(const float* __restrict__ x,
               const fx4* __restrict__ sstart,
               float* __restrict__ out) {
    int tid   = blockIdx.x * 256 + threadIdx.x;
    int fg    = tid & (FG - 1);
    int chunk = (tid >> 3) & (NC - 1);
    int b     = tid >> 12;

    size_t base = (size_t)(b * T + chunk * L) * FG + fg;
    const fx4* xp = reinterpret_cast<const fx4*>(x)   + base;
    fx4*       op = reinterpret_cast<fx4*>(out)       + base;

    fx4 s0 = sstart[tid];
    float sx = s0.x, sy = s0.y, sz = s0.z, sw = s0.w;
#pragma unroll 8
    for (int i = 0; i < L; ++i) {
        fx4 v = xp[(size_t)i * FG];
        sx = fmaf(ALPHA, sx, OMA * v.x);
        sy = fmaf(ALPHA, sy, OMA * v.y);
        sz = fmaf(ALPHA, sz, OMA * v.z);
        sw = fmaf(ALPHA, sw, OMA * v.w);
        fx4 o;
        o.x = (v.x - sx) * INV40;
        o.y = (v.y - sy) * INV40;
        o.z = (v.z - sz) * INV40;
        o.w = (v.w - sw) * INV40;
        __builtin_nontemporal_store(o, op + (size_t)i * FG);
    }
}

extern "C" void kernel_launch(void* const* d_in, const int* in_sizes, int n_in,
                              void* d_out, int out_size, void* d_ws, size_t ws_size,
                              hipStream_t stream) {
    const float* x     = (const float*)d_in[0];
    const float* state = (const float*)d_in[1];
    float* out = (float*)d_out;
    float* ws  = (float*)d_ws;

    float* c      = ws;                        // B*NC*F = 1M floats (4 MB)
    float* sstart = ws + (size_t)B * NC * F;   // another 4 MB

    const float aL  = (float)pow(0.99, (double)L);    // alpha^32
    const float aL8 = (float)pow(0.99, (double)(L * CPL));  // alpha^256

    ema_pass1<<<(B * NC * FG) / 256, 256, 0, stream>>>(x, (fx4*)c);
    ema_pass2<<<(B * F * 64) / 256, 256, 0, stream>>>(state, c, sstart, out + FEAT_N, aL, aL8);
    ema_pass3<<<(B * NC * FG) / 256, 256, 0, stream>>>(x, (const fx4*)sstart, out);
}